// Round 1
// baseline (597.304 us; speedup 1.0000x reference)
//
#include <hip/hip_runtime.h>
#include <hip/hip_bf16.h>
#include <stdint.h>

#define T_TOK 4096
#define H_DIM 1024
#define F_DIM 2816
#define E_NUM 8

typedef __attribute__((ext_vector_type(8))) __bf16 bf16x8;
typedef __attribute__((ext_vector_type(4))) float floatx4;

// round-to-nearest-even fp32 -> bf16, packed 2-at-a-time
__device__ __forceinline__ unsigned pack2bf16(float a, float b) {
  unsigned ua = __builtin_bit_cast(unsigned, a);
  unsigned ub = __builtin_bit_cast(unsigned, b);
  ua += 0x7fffu + ((ua >> 16) & 1u);
  ub += 0x7fffu + ((ub >> 16) & 1u);
  return (ua >> 16) | (ub & 0xffff0000u);
}

// XOR swizzle for [row][64 bf16] LDS tiles (128 B rows): kills the 16-way
// bank conflict on ds_read_b128 column slices. colb is byte offset in row.
__device__ __forceinline__ int swz(int row, int colb) {
  return (row * 128 + colb) ^ ((row & 7) << 4);
}

// ---------------- router: logits (fp32, exact), softmax top-2, build lists,
// ---------------- and emit x as bf16 for the expert GEMMs -------------------
__global__ __launch_bounds__(256) void router_kernel(
    const float* __restrict__ x, const float* __restrict__ gate,
    float* __restrict__ logits_out, __hip_bfloat16* __restrict__ xb,
    int* __restrict__ counts, int* __restrict__ idx_list,
    float* __restrict__ wgt_list)
{
  const int wv = threadIdx.x >> 6;
  const int lane = threadIdx.x & 63;
  const int t = blockIdx.x * 4 + wv;

  const float4* xr = (const float4*)(x + (size_t)t * H_DIM);
  const float4* g4 = (const float4*)gate;

  float acc[E_NUM];
#pragma unroll
  for (int e = 0; e < E_NUM; ++e) acc[e] = 0.f;

  unsigned* xbo = (unsigned*)(xb + (size_t)t * H_DIM);
#pragma unroll
  for (int j = 0; j < 4; ++j) {
    int i = j * 64 + lane;          // float4 index within the 1024-float row
    float4 xv = xr[i];
    uint2 pk;
    pk.x = pack2bf16(xv.x, xv.y);
    pk.y = pack2bf16(xv.z, xv.w);
    *(uint2*)(xbo + i * 2) = pk;
#pragma unroll
    for (int e = 0; e < E_NUM; ++e) {
      float4 gv = g4[e * 256 + i];
      acc[e] += xv.x * gv.x + xv.y * gv.y + xv.z * gv.z + xv.w * gv.w;
    }
  }
#pragma unroll
  for (int off = 32; off > 0; off >>= 1) {
#pragma unroll
    for (int e = 0; e < E_NUM; ++e) acc[e] += __shfl_xor(acc[e], off, 64);
  }

  if (lane == 0) {
#pragma unroll
    for (int e = 0; e < E_NUM; ++e) logits_out[(size_t)t * E_NUM + e] = acc[e];
    // top-1 (strict > keeps lowest index on ties, matching lax.top_k)
    int i0 = 0; float v0 = acc[0];
#pragma unroll
    for (int e = 1; e < E_NUM; ++e) if (acc[e] > v0) { v0 = acc[e]; i0 = e; }
    int i1 = -1; float v1 = -1e30f;
#pragma unroll
    for (int e = 0; e < E_NUM; ++e)
      if (e != i0 && acc[e] > v1) { v1 = acc[e]; i1 = e; }
    // renormalized top-2 weights (softmax denominator cancels)
    float p1 = __expf(v1 - v0);
    float w0 = 1.f / (1.f + p1);
    float w1 = p1 / (1.f + p1);
    int pos0 = atomicAdd(&counts[i0], 1);
    idx_list[i0 * T_TOK + pos0] = t;
    wgt_list[i0 * T_TOK + pos0] = w0;
    int pos1 = atomicAdd(&counts[i1], 1);
    idx_list[i1 * T_TOK + pos1] = t;
    wgt_list[i1 * T_TOK + pos1] = w1;
  }
}

__global__ void scan_kernel(const int* __restrict__ counts,
                            int* __restrict__ offsets) {
  if (threadIdx.x == 0) {
    int s = 0;
    for (int e = 0; e < E_NUM; ++e) { offsets[e] = s; s += counts[e]; }
  }
}

// ------------- GEMM1: hidden = silu(X @ W1^T) * (X @ W3^T), per expert ------
// X rows gathered via idx_list; W1/W3 fp32 converted to bf16 while staging.
__global__ __launch_bounds__(256) void gemm1_kernel(
    const __hip_bfloat16* __restrict__ xb,
    const float* __restrict__ w1, const float* __restrict__ w3,
    const int* __restrict__ counts, const int* __restrict__ offsets,
    const int* __restrict__ idx_list, __hip_bfloat16* __restrict__ hidden)
{
  const int e = blockIdx.z;
  const int n_e = counts[e];
  const int tm = blockIdx.y;
  if (tm * 128 >= n_e) return;
  const int tn = blockIdx.x;
  const int f0 = tn * 128;
  const int off_e = offsets[e];

  __shared__ short sA[128 * 64];
  __shared__ short sB1[128 * 64];
  __shared__ short sB3[128 * 64];
  __shared__ int s_row[128];

  const int tid = threadIdx.x;
  if (tid < 128) {
    int pos = tm * 128 + tid;
    int p = pos < n_e ? pos : n_e - 1;
    s_row[tid] = idx_list[e * T_TOK + p];
  }

  const int lane = tid & 63;
  const int wv = tid >> 6;
  const int wrow = (wv >> 1) * 64;
  const int wcol = (wv & 1) * 64;
  const int cc = tid & 7;        // 16B chunk column within 64-col row
  const int rbase = tid >> 3;    // staging row base

  floatx4 acc1[4][4], acc3[4][4];
#pragma unroll
  for (int m = 0; m < 4; ++m)
#pragma unroll
    for (int n = 0; n < 4; ++n)
#pragma unroll
      for (int r = 0; r < 4; ++r) { acc1[m][n][r] = 0.f; acc3[m][n][r] = 0.f; }

  const float* w1e = w1 + (size_t)e * F_DIM * H_DIM + (size_t)f0 * H_DIM;
  const float* w3e = w3 + (size_t)e * F_DIM * H_DIM + (size_t)f0 * H_DIM;

  for (int kt = 0; kt < H_DIM / 64; ++kt) {
    const int k0 = kt * 64;
    __syncthreads();
#pragma unroll
    for (int i = 0; i < 4; ++i) {
      int r = rbase + 32 * i;
      uint4 av = *(const uint4*)(xb + (size_t)s_row[r] * H_DIM + k0 + cc * 8);
      *(uint4*)((char*)sA + swz(r, cc * 16)) = av;

      const float4* p1 = (const float4*)(w1e + (size_t)r * H_DIM + k0 + cc * 8);
      float4 a1 = p1[0], b1 = p1[1];
      uint4 pb1;
      pb1.x = pack2bf16(a1.x, a1.y); pb1.y = pack2bf16(a1.z, a1.w);
      pb1.z = pack2bf16(b1.x, b1.y); pb1.w = pack2bf16(b1.z, b1.w);
      *(uint4*)((char*)sB1 + swz(r, cc * 16)) = pb1;

      const float4* p3 = (const float4*)(w3e + (size_t)r * H_DIM + k0 + cc * 8);
      float4 a3 = p3[0], b3 = p3[1];
      uint4 pb3;
      pb3.x = pack2bf16(a3.x, a3.y); pb3.y = pack2bf16(a3.z, a3.w);
      pb3.z = pack2bf16(b3.x, b3.y); pb3.w = pack2bf16(b3.z, b3.w);
      *(uint4*)((char*)sB3 + swz(r, cc * 16)) = pb3;
    }
    __syncthreads();
#pragma unroll
    for (int kk = 0; kk < 2; ++kk) {
      const int colb = kk * 64 + (lane >> 4) * 16;
      bf16x8 af[4], bf1[4], bf3[4];
#pragma unroll
      for (int m = 0; m < 4; ++m)
        af[m] = *(const bf16x8*)((const char*)sA +
                                 swz(wrow + m * 16 + (lane & 15), colb));
#pragma unroll
      for (int n = 0; n < 4; ++n) {
        bf1[n] = *(const bf16x8*)((const char*)sB1 +
                                  swz(wcol + n * 16 + (lane & 15), colb));
        bf3[n] = *(const bf16x8*)((const char*)sB3 +
                                  swz(wcol + n * 16 + (lane & 15), colb));
      }
#pragma unroll
      for (int m = 0; m < 4; ++m)
#pragma unroll
        for (int n = 0; n < 4; ++n) {
          acc1[m][n] = __builtin_amdgcn_mfma_f32_16x16x32_bf16(
              af[m], bf1[n], acc1[m][n], 0, 0, 0);
          acc3[m][n] = __builtin_amdgcn_mfma_f32_16x16x32_bf16(
              af[m], bf3[n], acc3[m][n], 0, 0, 0);
        }
    }
  }

#pragma unroll
  for (int m = 0; m < 4; ++m) {
#pragma unroll
    for (int r = 0; r < 4; ++r) {
      int rl = wrow + m * 16 + ((lane >> 4) << 2) + r;
      int pos = tm * 128 + rl;
      if (pos < n_e) {
        __hip_bfloat16* hrow = hidden + (size_t)(off_e + pos) * F_DIM + f0;
#pragma unroll
        for (int n = 0; n < 4; ++n) {
          float h1 = acc1[m][n][r];
          float h3 = acc3[m][n][r];
          float h = (h1 / (1.f + __expf(-h1))) * h3;   // silu(h1) * h3
          hrow[wcol + n * 16 + (lane & 15)] = __float2bfloat16(h);
        }
      }
    }
  }
}

// ------------- GEMM2: y = hidden @ W2^T, scale by combine weight, ----------
// ------------- atomicAdd-scatter into out --------------------------------
__global__ __launch_bounds__(256) void gemm2_kernel(
    const __hip_bfloat16* __restrict__ hidden, const float* __restrict__ w2,
    const int* __restrict__ counts, const int* __restrict__ offsets,
    const int* __restrict__ idx_list, const float* __restrict__ wgt_list,
    float* __restrict__ out)
{
  const int e = blockIdx.z;
  const int n_e = counts[e];
  const int tm = blockIdx.y;
  if (tm * 128 >= n_e) return;
  const int tn = blockIdx.x;
  const int n0 = tn * 128;
  const int off_e = offsets[e];

  __shared__ short sA[128 * 64];
  __shared__ short sB[128 * 64];
  __shared__ int s_tok[128];
  __shared__ float s_wgt[128];

  const int tid = threadIdx.x;
  if (tid < 128) {
    int pos = tm * 128 + tid;
    if (pos < n_e) {
      s_tok[tid] = idx_list[e * T_TOK + pos];
      s_wgt[tid] = wgt_list[e * T_TOK + pos];
    } else {
      s_tok[tid] = -1;
      s_wgt[tid] = 0.f;
    }
  }

  const int lane = tid & 63;
  const int wv = tid >> 6;
  const int wrow = (wv >> 1) * 64;
  const int wcol = (wv & 1) * 64;
  const int cc = tid & 7;
  const int rbase = tid >> 3;

  floatx4 acc[4][4];
#pragma unroll
  for (int m = 0; m < 4; ++m)
#pragma unroll
    for (int n = 0; n < 4; ++n)
#pragma unroll
      for (int r = 0; r < 4; ++r) acc[m][n][r] = 0.f;

  const float* w2e = w2 + (size_t)e * H_DIM * F_DIM + (size_t)n0 * F_DIM;

  for (int kt = 0; kt < F_DIM / 64; ++kt) {   // 44 K-tiles
    const int k0 = kt * 64;
    __syncthreads();
#pragma unroll
    for (int i = 0; i < 4; ++i) {
      int r = rbase + 32 * i;
      int pos = tm * 128 + r;
      int pr = pos < n_e ? pos : n_e - 1;     // clamp: garbage rows discarded
      uint4 av = *(const uint4*)(hidden + (size_t)(off_e + pr) * F_DIM +
                                 k0 + cc * 8);
      *(uint4*)((char*)sA + swz(r, cc * 16)) = av;

      const float4* pb = (const float4*)(w2e + (size_t)r * F_DIM + k0 + cc * 8);
      float4 ba = pb[0], bb = pb[1];
      uint4 pk;
      pk.x = pack2bf16(ba.x, ba.y); pk.y = pack2bf16(ba.z, ba.w);
      pk.z = pack2bf16(bb.x, bb.y); pk.w = pack2bf16(bb.z, bb.w);
      *(uint4*)((char*)sB + swz(r, cc * 16)) = pk;
    }
    __syncthreads();
#pragma unroll
    for (int kk = 0; kk < 2; ++kk) {
      const int colb = kk * 64 + (lane >> 4) * 16;
      bf16x8 af[4], bf[4];
#pragma unroll
      for (int m = 0; m < 4; ++m)
        af[m] = *(const bf16x8*)((const char*)sA +
                                 swz(wrow + m * 16 + (lane & 15), colb));
#pragma unroll
      for (int n = 0; n < 4; ++n)
        bf[n] = *(const bf16x8*)((const char*)sB +
                                 swz(wcol + n * 16 + (lane & 15), colb));
#pragma unroll
      for (int m = 0; m < 4; ++m)
#pragma unroll
        for (int n = 0; n < 4; ++n)
          acc[m][n] = __builtin_amdgcn_mfma_f32_16x16x32_bf16(
              af[m], bf[n], acc[m][n], 0, 0, 0);
    }
  }

#pragma unroll
  for (int m = 0; m < 4; ++m) {
#pragma unroll
    for (int r = 0; r < 4; ++r) {
      int rl = wrow + m * 16 + ((lane >> 4) << 2) + r;
      int tok = s_tok[rl];
      if (tok >= 0) {
        float wgt = s_wgt[rl];
        float* orow = out + (size_t)tok * H_DIM + n0;
#pragma unroll
        for (int n = 0; n < 4; ++n)
          atomicAdd(&orow[wcol + n * 16 + (lane & 15)], wgt * acc[m][n][r]);
      }
    }
  }
}

extern "C" void kernel_launch(void* const* d_in, const int* in_sizes, int n_in,
                              void* d_out, int out_size, void* d_ws,
                              size_t ws_size, hipStream_t stream) {
  const float* x = (const float*)d_in[0];
  const float* gate = (const float*)d_in[1];
  const float* w1 = (const float*)d_in[2];
  const float* w3 = (const float*)d_in[3];
  const float* w2 = (const float*)d_in[4];

  float* out = (float*)d_out;                        // [T, H]
  float* logits = out + (size_t)T_TOK * H_DIM;       // [T, E]

  char* ws = (char*)d_ws;
  int* counts = (int*)ws;                            // 8 ints
  int* offsets = counts + 8;                         // 8 ints
  int* idx_list = (int*)(ws + 256);                  // [E][T]
  float* wgt_list = (float*)(ws + 256 + (size_t)E_NUM * T_TOK * 4);
  __hip_bfloat16* xb =
      (__hip_bfloat16*)(ws + 256 + (size_t)2 * E_NUM * T_TOK * 4);
  __hip_bfloat16* hidden =
      (__hip_bfloat16*)(ws + 256 + (size_t)2 * E_NUM * T_TOK * 4 +
                        (size_t)T_TOK * H_DIM * 2);  // [8192, F] bf16

  hipMemsetAsync(counts, 0, 64, stream);
  hipMemsetAsync(out, 0, (size_t)T_TOK * H_DIM * sizeof(float), stream);

  router_kernel<<<T_TOK / 4, 256, 0, stream>>>(x, gate, logits, xb, counts,
                                               idx_list, wgt_list);
  scan_kernel<<<1, 64, 0, stream>>>(counts, offsets);
  gemm1_kernel<<<dim3(F_DIM / 128, T_TOK / 128, E_NUM), 256, 0, stream>>>(
      xb, w1, w3, counts, offsets, idx_list, hidden);
  gemm2_kernel<<<dim3(H_DIM / 128, T_TOK / 128, E_NUM), 256, 0, stream>>>(
      hidden, w2, counts, offsets, idx_list, wgt_list, out);
}

// Round 3
// 517.406 us; speedup vs baseline: 1.1544x; 1.1544x over previous
//
#include <hip/hip_runtime.h>
#include <hip/hip_bf16.h>
#include <stdint.h>

#define T_TOK 4096
#define H_DIM 1024
#define F_DIM 2816
#define E_NUM 8

typedef __attribute__((ext_vector_type(8))) __bf16 bf16x8;
typedef __attribute__((ext_vector_type(4))) float floatx4;
typedef __attribute__((address_space(3))) char lds_char;
typedef __attribute__((address_space(1))) const char glb_char;

// async 16B global->LDS (dest = wave-uniform base + lane*16)
__device__ __forceinline__ void gload16(const void* g, void* l) {
  __builtin_amdgcn_global_load_lds((glb_char*)g, (lds_char*)l, 16, 0, 0);
}

// round-to-nearest-even fp32 -> bf16, packed 2-at-a-time
__device__ __forceinline__ unsigned pack2bf16(float a, float b) {
  unsigned ua = __builtin_bit_cast(unsigned, a);
  unsigned ub = __builtin_bit_cast(unsigned, b);
  ua += 0x7fffu + ((ua >> 16) & 1u);
  ub += 0x7fffu + ((ub >> 16) & 1u);
  return (ua >> 16) | (ub & 0xffff0000u);
}

// XOR swizzle for [row][64 bf16] LDS tiles (128 B rows): kills the 16-way
// bank conflict on ds_read_b128 column slices. colb is byte offset in row.
__device__ __forceinline__ int swz(int row, int colb) {
  return (row * 128 + colb) ^ ((row & 7) << 4);
}

// ---------------- fp32 -> bf16 weight conversion (grid-stride) --------------
__global__ __launch_bounds__(256) void convert_kernel(
    const float* __restrict__ src, __hip_bfloat16* __restrict__ dst,
    int nchunk8) {
  int i = blockIdx.x * blockDim.x + threadIdx.x;
  const int stride = gridDim.x * blockDim.x;
  for (; i < nchunk8; i += stride) {
    const float4* s = (const float4*)(src + (size_t)i * 8);
    float4 a = s[0], b = s[1];
    uint4 p;
    p.x = pack2bf16(a.x, a.y); p.y = pack2bf16(a.z, a.w);
    p.z = pack2bf16(b.x, b.y); p.w = pack2bf16(b.z, b.w);
    *(uint4*)((char*)dst + (size_t)i * 16) = p;
  }
}

// ---------------- router: logits (fp32, exact), softmax top-2, build lists,
// ---------------- and emit x as bf16 for the expert GEMMs -------------------
__global__ __launch_bounds__(256) void router_kernel(
    const float* __restrict__ x, const float* __restrict__ gate,
    float* __restrict__ logits_out, __hip_bfloat16* __restrict__ xb,
    int* __restrict__ counts, int* __restrict__ idx_list,
    float* __restrict__ wgt_list)
{
  const int wv = threadIdx.x >> 6;
  const int lane = threadIdx.x & 63;
  const int t = blockIdx.x * 4 + wv;

  const float4* xr = (const float4*)(x + (size_t)t * H_DIM);
  const float4* g4 = (const float4*)gate;

  float acc[E_NUM];
#pragma unroll
  for (int e = 0; e < E_NUM; ++e) acc[e] = 0.f;

  unsigned* xbo = (unsigned*)(xb + (size_t)t * H_DIM);
#pragma unroll
  for (int j = 0; j < 4; ++j) {
    int i = j * 64 + lane;          // float4 index within the 1024-float row
    float4 xv = xr[i];
    uint2 pk;
    pk.x = pack2bf16(xv.x, xv.y);
    pk.y = pack2bf16(xv.z, xv.w);
    *(uint2*)(xbo + i * 2) = pk;
#pragma unroll
    for (int e = 0; e < E_NUM; ++e) {
      float4 gv = g4[e * 256 + i];
      acc[e] += xv.x * gv.x + xv.y * gv.y + xv.z * gv.z + xv.w * gv.w;
    }
  }
#pragma unroll
  for (int off = 32; off > 0; off >>= 1) {
#pragma unroll
    for (int e = 0; e < E_NUM; ++e) acc[e] += __shfl_xor(acc[e], off, 64);
  }

  if (lane == 0) {
#pragma unroll
    for (int e = 0; e < E_NUM; ++e) logits_out[(size_t)t * E_NUM + e] = acc[e];
    // top-1 (strict > keeps lowest index on ties, matching lax.top_k)
    int i0 = 0; float v0 = acc[0];
#pragma unroll
    for (int e = 1; e < E_NUM; ++e) if (acc[e] > v0) { v0 = acc[e]; i0 = e; }
    int i1 = -1; float v1 = -1e30f;
#pragma unroll
    for (int e = 0; e < E_NUM; ++e)
      if (e != i0 && acc[e] > v1) { v1 = acc[e]; i1 = e; }
    // renormalized top-2 weights (softmax denominator cancels)
    float p1 = __expf(v1 - v0);
    float w0 = 1.f / (1.f + p1);
    float w1 = p1 / (1.f + p1);
    int pos0 = atomicAdd(&counts[i0], 1);
    idx_list[i0 * T_TOK + pos0] = t;
    wgt_list[i0 * T_TOK + pos0] = w0;
    int pos1 = atomicAdd(&counts[i1], 1);
    idx_list[i1 * T_TOK + pos1] = t;
    wgt_list[i1 * T_TOK + pos1] = w1;
  }
}

__global__ void scan_kernel(const int* __restrict__ counts,
                            int* __restrict__ offsets) {
  if (threadIdx.x == 0) {
    int s = 0;
    for (int e = 0; e < E_NUM; ++e) { offsets[e] = s; s += counts[e]; }
  }
}

// ------------- GEMM1 (gload_lds + explicit vmcnt drain) ---------------------
// hidden = silu(X W1^T) * (X W3^T); all operands bf16.
__global__ __launch_bounds__(256) void gemm1_kernel(
    const __hip_bfloat16* __restrict__ xb,
    const __hip_bfloat16* __restrict__ w1b,
    const __hip_bfloat16* __restrict__ w3b,
    const int* __restrict__ counts, const int* __restrict__ offsets,
    const int* __restrict__ idx_list, __hip_bfloat16* __restrict__ hidden)
{
  const int e = blockIdx.z;
  const int n_e = counts[e];
  const int tm = blockIdx.y;
  if (n_e == 0 || tm * 128 >= n_e) return;
  const int tn = blockIdx.x;
  const int f0 = tn * 128;
  const int off_e = offsets[e];

  __shared__ char sA[16384];
  __shared__ char sB1[16384];
  __shared__ char sB3[16384];

  const int tid = threadIdx.x;
  const int lane = tid & 63;
  const int wv = tid >> 6;
  const int wrow = (wv >> 1) * 64;
  const int wcol = (wv & 1) * 64;
  // source chunk column, pre-swizzled so linear LDS + swizzled read match
  const int csw = ((lane & 7) ^ (lane >> 3)) * 16;
  const int rsub = lane >> 3;

  const char* xbp = (const char*)xb;
  size_t arow[4];
#pragma unroll
  for (int i = 0; i < 4; ++i) {
    int r = wv * 32 + i * 8 + rsub;
    int pos = tm * 128 + r;
    int p = pos < n_e ? pos : n_e - 1;
    arow[i] = (size_t)idx_list[e * T_TOK + p] * (H_DIM * 2);
  }
  const char* w1p = (const char*)w1b + ((size_t)e * F_DIM + f0) * (H_DIM * 2);
  const char* w3p = (const char*)w3b + ((size_t)e * F_DIM + f0) * (H_DIM * 2);

  floatx4 acc1[4][4], acc3[4][4];
#pragma unroll
  for (int m = 0; m < 4; ++m)
#pragma unroll
    for (int n = 0; n < 4; ++n)
#pragma unroll
      for (int r = 0; r < 4; ++r) { acc1[m][n][r] = 0.f; acc3[m][n][r] = 0.f; }

  for (int kt = 0; kt < H_DIM / 64; ++kt) {
    const int kb = kt * 128;   // byte offset of k0 within a 2048-B row
    __syncthreads();           // prev iteration's readers done
#pragma unroll
    for (int i = 0; i < 4; ++i) {
      int r = wv * 32 + i * 8 + rsub;
      int ldsoff = wv * 4096 + i * 1024;
      gload16(xbp + arow[i] + kb + csw, sA + ldsoff);
      gload16(w1p + (size_t)r * (H_DIM * 2) + kb + csw, sB1 + ldsoff);
      gload16(w3p + (size_t)r * (H_DIM * 2) + kb + csw, sB3 + ldsoff);
    }
    // Explicit DMA drain: do NOT rely on the compiler emitting vmcnt(0)
    // before s_barrier for global_load_lds (suspected R2 replay race).
    asm volatile("s_waitcnt vmcnt(0)" ::: "memory");
    __syncthreads();
#pragma unroll
    for (int kk = 0; kk < 2; ++kk) {
      const int colb = kk * 64 + (lane >> 4) * 16;
      bf16x8 af[4], bf1[4], bf3[4];
#pragma unroll
      for (int m = 0; m < 4; ++m)
        af[m] = *(const bf16x8*)(sA + swz(wrow + m * 16 + (lane & 15), colb));
#pragma unroll
      for (int n = 0; n < 4; ++n) {
        bf1[n] = *(const bf16x8*)(sB1 + swz(wcol + n * 16 + (lane & 15), colb));
        bf3[n] = *(const bf16x8*)(sB3 + swz(wcol + n * 16 + (lane & 15), colb));
      }
#pragma unroll
      for (int m = 0; m < 4; ++m)
#pragma unroll
        for (int n = 0; n < 4; ++n) {
          acc1[m][n] = __builtin_amdgcn_mfma_f32_16x16x32_bf16(
              af[m], bf1[n], acc1[m][n], 0, 0, 0);
          acc3[m][n] = __builtin_amdgcn_mfma_f32_16x16x32_bf16(
              af[m], bf3[n], acc3[m][n], 0, 0, 0);
        }
    }
  }

#pragma unroll
  for (int m = 0; m < 4; ++m) {
#pragma unroll
    for (int r = 0; r < 4; ++r) {
      int rl = wrow + m * 16 + ((lane >> 4) << 2) + r;
      int pos = tm * 128 + rl;
      if (pos < n_e) {
        __hip_bfloat16* hrow = hidden + (size_t)(off_e + pos) * F_DIM + f0;
#pragma unroll
        for (int n = 0; n < 4; ++n) {
          float h1 = acc1[m][n][r];
          float h3 = acc3[m][n][r];
          float h = (h1 / (1.f + __expf(-h1))) * h3;   // silu(h1) * h3
          hrow[wcol + n * 16 + (lane & 15)] = __float2bfloat16(h);
        }
      }
    }
  }
}

// ------------- GEMM2 (conservative, R1-proven structure, bf16 staging) ------
// y = hidden @ W2^T, scaled by combine weight, atomicAdd scatter into out.
__global__ __launch_bounds__(256) void gemm2_kernel(
    const __hip_bfloat16* __restrict__ hidden,
    const __hip_bfloat16* __restrict__ w2b,
    const int* __restrict__ counts, const int* __restrict__ offsets,
    const int* __restrict__ idx_list, const float* __restrict__ wgt_list,
    float* __restrict__ out)
{
  const int e = blockIdx.z;
  const int n_e = counts[e];
  const int tm = blockIdx.y;
  if (n_e == 0 || tm * 128 >= n_e) return;
  const int tn = blockIdx.x;
  const int n0 = tn * 128;
  const int off_e = offsets[e];

  __shared__ short sA[128 * 64];
  __shared__ short sB[128 * 64];
  __shared__ int s_tok[128];
  __shared__ float s_wgt[128];

  const int tid = threadIdx.x;
  if (tid < 128) {
    int pos = tm * 128 + tid;
    if (pos < n_e) {
      s_tok[tid] = idx_list[e * T_TOK + pos];
      s_wgt[tid] = wgt_list[e * T_TOK + pos];
    } else {
      s_tok[tid] = -1;
      s_wgt[tid] = 0.f;
    }
  }
  const int lane = tid & 63;
  const int wv = tid >> 6;
  const int wrow = (wv >> 1) * 64;
  const int wcol = (wv & 1) * 64;
  const int cc = tid & 7;
  const int rbase = tid >> 3;

  floatx4 acc[4][4];
#pragma unroll
  for (int m = 0; m < 4; ++m)
#pragma unroll
    for (int n = 0; n < 4; ++n)
#pragma unroll
      for (int r = 0; r < 4; ++r) acc[m][n][r] = 0.f;

  const __hip_bfloat16* w2e = w2b + ((size_t)e * H_DIM + n0) * F_DIM;

  for (int kt = 0; kt < F_DIM / 64; ++kt) {   // 44 K-tiles
    const int k0 = kt * 64;
    __syncthreads();
#pragma unroll
    for (int i = 0; i < 4; ++i) {
      int r = rbase + 32 * i;
      int pos = tm * 128 + r;
      int pr = pos < n_e ? pos : n_e - 1;     // clamp: garbage rows discarded
      uint4 av = *(const uint4*)(hidden + (size_t)(off_e + pr) * F_DIM +
                                 k0 + cc * 8);
      *(uint4*)((char*)sA + swz(r, cc * 16)) = av;
      uint4 bv = *(const uint4*)(w2e + (size_t)r * F_DIM + k0 + cc * 8);
      *(uint4*)((char*)sB + swz(r, cc * 16)) = bv;
    }
    __syncthreads();
#pragma unroll
    for (int kk = 0; kk < 2; ++kk) {
      const int colb = kk * 64 + (lane >> 4) * 16;
      bf16x8 af[4], bf[4];
#pragma unroll
      for (int m = 0; m < 4; ++m)
        af[m] = *(const bf16x8*)((const char*)sA +
                                 swz(wrow + m * 16 + (lane & 15), colb));
#pragma unroll
      for (int n = 0; n < 4; ++n)
        bf[n] = *(const bf16x8*)((const char*)sB +
                                 swz(wcol + n * 16 + (lane & 15), colb));
#pragma unroll
      for (int m = 0; m < 4; ++m)
#pragma unroll
        for (int n = 0; n < 4; ++n)
          acc[m][n] = __builtin_amdgcn_mfma_f32_16x16x32_bf16(
              af[m], bf[n], acc[m][n], 0, 0, 0);
    }
  }

#pragma unroll
  for (int m = 0; m < 4; ++m) {
#pragma unroll
    for (int r = 0; r < 4; ++r) {
      int rl = wrow + m * 16 + ((lane >> 4) << 2) + r;
      int tok = s_tok[rl];
      if (tok >= 0) {
        float wgt = s_wgt[rl];
        float* orow = out + (size_t)tok * H_DIM + n0;
#pragma unroll
        for (int n = 0; n < 4; ++n)
          atomicAdd(&orow[wcol + n * 16 + (lane & 15)], wgt * acc[m][n][r]);
      }
    }
  }
}

// =================== fallback path (round-1 kernels, fused convert) =========
__global__ __launch_bounds__(256) void gemm1_fb(
    const __hip_bfloat16* __restrict__ xb,
    const float* __restrict__ w1, const float* __restrict__ w3,
    const int* __restrict__ counts, const int* __restrict__ offsets,
    const int* __restrict__ idx_list, __hip_bfloat16* __restrict__ hidden)
{
  const int e = blockIdx.z;
  const int n_e = counts[e];
  const int tm = blockIdx.y;
  if (n_e == 0 || tm * 128 >= n_e) return;
  const int tn = blockIdx.x;
  const int f0 = tn * 128;
  const int off_e = offsets[e];

  __shared__ short sA[128 * 64];
  __shared__ short sB1[128 * 64];
  __shared__ short sB3[128 * 64];
  __shared__ int s_row[128];

  const int tid = threadIdx.x;
  if (tid < 128) {
    int pos = tm * 128 + tid;
    int p = pos < n_e ? pos : n_e - 1;
    s_row[tid] = idx_list[e * T_TOK + p];
  }
  const int lane = tid & 63;
  const int wv = tid >> 6;
  const int wrow = (wv >> 1) * 64;
  const int wcol = (wv & 1) * 64;
  const int cc = tid & 7;
  const int rbase = tid >> 3;

  floatx4 acc1[4][4], acc3[4][4];
#pragma unroll
  for (int m = 0; m < 4; ++m)
#pragma unroll
    for (int n = 0; n < 4; ++n)
#pragma unroll
      for (int r = 0; r < 4; ++r) { acc1[m][n][r] = 0.f; acc3[m][n][r] = 0.f; }

  const float* w1e = w1 + (size_t)e * F_DIM * H_DIM + (size_t)f0 * H_DIM;
  const float* w3e = w3 + (size_t)e * F_DIM * H_DIM + (size_t)f0 * H_DIM;

  for (int kt = 0; kt < H_DIM / 64; ++kt) {
    const int k0 = kt * 64;
    __syncthreads();
#pragma unroll
    for (int i = 0; i < 4; ++i) {
      int r = rbase + 32 * i;
      uint4 av = *(const uint4*)(xb + (size_t)s_row[r] * H_DIM + k0 + cc * 8);
      *(uint4*)((char*)sA + swz(r, cc * 16)) = av;
      const float4* p1 = (const float4*)(w1e + (size_t)r * H_DIM + k0 + cc * 8);
      float4 a1 = p1[0], b1 = p1[1];
      uint4 pb1;
      pb1.x = pack2bf16(a1.x, a1.y); pb1.y = pack2bf16(a1.z, a1.w);
      pb1.z = pack2bf16(b1.x, b1.y); pb1.w = pack2bf16(b1.z, b1.w);
      *(uint4*)((char*)sB1 + swz(r, cc * 16)) = pb1;
      const float4* p3 = (const float4*)(w3e + (size_t)r * H_DIM + k0 + cc * 8);
      float4 a3 = p3[0], b3 = p3[1];
      uint4 pb3;
      pb3.x = pack2bf16(a3.x, a3.y); pb3.y = pack2bf16(a3.z, a3.w);
      pb3.z = pack2bf16(b3.x, b3.y); pb3.w = pack2bf16(b3.z, b3.w);
      *(uint4*)((char*)sB3 + swz(r, cc * 16)) = pb3;
    }
    __syncthreads();
#pragma unroll
    for (int kk = 0; kk < 2; ++kk) {
      const int colb = kk * 64 + (lane >> 4) * 16;
      bf16x8 af[4], bf1[4], bf3[4];
#pragma unroll
      for (int m = 0; m < 4; ++m)
        af[m] = *(const bf16x8*)((const char*)sA +
                                 swz(wrow + m * 16 + (lane & 15), colb));
#pragma unroll
      for (int n = 0; n < 4; ++n) {
        bf1[n] = *(const bf16x8*)((const char*)sB1 +
                                  swz(wcol + n * 16 + (lane & 15), colb));
        bf3[n] = *(const bf16x8*)((const char*)sB3 +
                                  swz(wcol + n * 16 + (lane & 15), colb));
      }
#pragma unroll
      for (int m = 0; m < 4; ++m)
#pragma unroll
        for (int n = 0; n < 4; ++n) {
          acc1[m][n] = __builtin_amdgcn_mfma_f32_16x16x32_bf16(
              af[m], bf1[n], acc1[m][n], 0, 0, 0);
          acc3[m][n] = __builtin_amdgcn_mfma_f32_16x16x32_bf16(
              af[m], bf3[n], acc3[m][n], 0, 0, 0);
        }
    }
  }
#pragma unroll
  for (int m = 0; m < 4; ++m) {
#pragma unroll
    for (int r = 0; r < 4; ++r) {
      int rl = wrow + m * 16 + ((lane >> 4) << 2) + r;
      int pos = tm * 128 + rl;
      if (pos < n_e) {
        __hip_bfloat16* hrow = hidden + (size_t)(off_e + pos) * F_DIM + f0;
#pragma unroll
        for (int n = 0; n < 4; ++n) {
          float h1 = acc1[m][n][r];
          float h3 = acc3[m][n][r];
          float h = (h1 / (1.f + __expf(-h1))) * h3;
          hrow[wcol + n * 16 + (lane & 15)] = __float2bfloat16(h);
        }
      }
    }
  }
}

__global__ __launch_bounds__(256) void gemm2_fb(
    const __hip_bfloat16* __restrict__ hidden, const float* __restrict__ w2,
    const int* __restrict__ counts, const int* __restrict__ offsets,
    const int* __restrict__ idx_list, const float* __restrict__ wgt_list,
    float* __restrict__ out)
{
  const int e = blockIdx.z;
  const int n_e = counts[e];
  const int tm = blockIdx.y;
  if (n_e == 0 || tm * 128 >= n_e) return;
  const int tn = blockIdx.x;
  const int n0 = tn * 128;
  const int off_e = offsets[e];

  __shared__ short sA[128 * 64];
  __shared__ short sB[128 * 64];
  __shared__ int s_tok[128];
  __shared__ float s_wgt[128];

  const int tid = threadIdx.x;
  if (tid < 128) {
    int pos = tm * 128 + tid;
    if (pos < n_e) {
      s_tok[tid] = idx_list[e * T_TOK + pos];
      s_wgt[tid] = wgt_list[e * T_TOK + pos];
    } else {
      s_tok[tid] = -1;
      s_wgt[tid] = 0.f;
    }
  }
  const int lane = tid & 63;
  const int wv = tid >> 6;
  const int wrow = (wv >> 1) * 64;
  const int wcol = (wv & 1) * 64;
  const int cc = tid & 7;
  const int rbase = tid >> 3;

  floatx4 acc[4][4];
#pragma unroll
  for (int m = 0; m < 4; ++m)
#pragma unroll
    for (int n = 0; n < 4; ++n)
#pragma unroll
      for (int r = 0; r < 4; ++r) acc[m][n][r] = 0.f;

  const float* w2e = w2 + (size_t)e * H_DIM * F_DIM + (size_t)n0 * F_DIM;

  for (int kt = 0; kt < F_DIM / 64; ++kt) {
    const int k0 = kt * 64;
    __syncthreads();
#pragma unroll
    for (int i = 0; i < 4; ++i) {
      int r = rbase + 32 * i;
      int pos = tm * 128 + r;
      int pr = pos < n_e ? pos : n_e - 1;
      uint4 av = *(const uint4*)(hidden + (size_t)(off_e + pr) * F_DIM +
                                 k0 + cc * 8);
      *(uint4*)((char*)sA + swz(r, cc * 16)) = av;
      const float4* pb = (const float4*)(w2e + (size_t)r * F_DIM + k0 + cc * 8);
      float4 ba = pb[0], bb = pb[1];
      uint4 pk;
      pk.x = pack2bf16(ba.x, ba.y); pk.y = pack2bf16(ba.z, ba.w);
      pk.z = pack2bf16(bb.x, bb.y); pk.w = pack2bf16(bb.z, bb.w);
      *(uint4*)((char*)sB + swz(r, cc * 16)) = pk;
    }
    __syncthreads();
#pragma unroll
    for (int kk = 0; kk < 2; ++kk) {
      const int colb = kk * 64 + (lane >> 4) * 16;
      bf16x8 af[4], bf[4];
#pragma unroll
      for (int m = 0; m < 4; ++m)
        af[m] = *(const bf16x8*)((const char*)sA +
                                 swz(wrow + m * 16 + (lane & 15), colb));
#pragma unroll
      for (int n = 0; n < 4; ++n)
        bf[n] = *(const bf16x8*)((const char*)sB +
                                 swz(wcol + n * 16 + (lane & 15), colb));
#pragma unroll
      for (int m = 0; m < 4; ++m)
#pragma unroll
        for (int n = 0; n < 4; ++n)
          acc[m][n] = __builtin_amdgcn_mfma_f32_16x16x32_bf16(
              af[m], bf[n], acc[m][n], 0, 0, 0);
    }
  }
#pragma unroll
  for (int m = 0; m < 4; ++m) {
#pragma unroll
    for (int r = 0; r < 4; ++r) {
      int rl = wrow + m * 16 + ((lane >> 4) << 2) + r;
      int tok = s_tok[rl];
      if (tok >= 0) {
        float wgt = s_wgt[rl];
        float* orow = out + (size_t)tok * H_DIM + n0;
#pragma unroll
        for (int n = 0; n < 4; ++n)
          atomicAdd(&orow[wcol + n * 16 + (lane & 15)], wgt * acc[m][n][r]);
      }
    }
  }
}

extern "C" void kernel_launch(void* const* d_in, const int* in_sizes, int n_in,
                              void* d_out, int out_size, void* d_ws,
                              size_t ws_size, hipStream_t stream) {
  const float* x = (const float*)d_in[0];
  const float* gate = (const float*)d_in[1];
  const float* w1 = (const float*)d_in[2];
  const float* w3 = (const float*)d_in[3];
  const float* w2 = (const float*)d_in[4];

  float* out = (float*)d_out;                        // [T, H]
  float* logits = out + (size_t)T_TOK * H_DIM;       // [T, E]

  char* ws = (char*)d_ws;
  const size_t WEB = (size_t)E_NUM * F_DIM * H_DIM * 2;  // bf16 weight bytes
  const size_t o_idx = 256;
  const size_t o_wgt = o_idx + (size_t)E_NUM * T_TOK * 4;
  const size_t o_xb  = o_wgt + (size_t)E_NUM * T_TOK * 4;   // 16B aligned
  const size_t o_hid = o_xb + (size_t)T_TOK * H_DIM * 2;
  const size_t o_w1b = o_hid + (size_t)2 * T_TOK * F_DIM * 2;
  const size_t o_w3b = o_w1b + WEB;
  const size_t o_w2b = o_w3b + WEB;
  const size_t need  = o_w2b + WEB;                         // ~193 MB

  int* counts = (int*)ws;
  int* offsets = counts + 8;
  int* idx_list = (int*)(ws + o_idx);
  float* wgt_list = (float*)(ws + o_wgt);
  __hip_bfloat16* xb = (__hip_bfloat16*)(ws + o_xb);
  __hip_bfloat16* hidden = (__hip_bfloat16*)(ws + o_hid);

  hipMemsetAsync(counts, 0, 64, stream);
  hipMemsetAsync(out, 0, (size_t)T_TOK * H_DIM * sizeof(float), stream);

  if (ws_size >= need) {
    __hip_bfloat16* w1b = (__hip_bfloat16*)(ws + o_w1b);
    __hip_bfloat16* w3b = (__hip_bfloat16*)(ws + o_w3b);
    __hip_bfloat16* w2b = (__hip_bfloat16*)(ws + o_w2b);

    const int NCH = E_NUM * F_DIM * H_DIM / 8;
    convert_kernel<<<2048, 256, 0, stream>>>(w1, w1b, NCH);
    convert_kernel<<<2048, 256, 0, stream>>>(w3, w3b, NCH);
    convert_kernel<<<2048, 256, 0, stream>>>(w2, w2b, NCH);
    router_kernel<<<T_TOK / 4, 256, 0, stream>>>(x, gate, logits, xb, counts,
                                                 idx_list, wgt_list);
    scan_kernel<<<1, 64, 0, stream>>>(counts, offsets);
    gemm1_kernel<<<dim3(F_DIM / 128, T_TOK / 128, E_NUM), 256, 0, stream>>>(
        xb, w1b, w3b, counts, offsets, idx_list, hidden);
    gemm2_kernel<<<dim3(H_DIM / 128, T_TOK / 128, E_NUM), 256, 0, stream>>>(
        hidden, w2b, counts, offsets, idx_list, wgt_list, out);
  } else {
    router_kernel<<<T_TOK / 4, 256, 0, stream>>>(x, gate, logits, xb, counts,
                                                 idx_list, wgt_list);
    scan_kernel<<<1, 64, 0, stream>>>(counts, offsets);
    gemm1_fb<<<dim3(F_DIM / 128, T_TOK / 128, E_NUM), 256, 0, stream>>>(
        xb, w1, w3, counts, offsets, idx_list, hidden);
    gemm2_fb<<<dim3(H_DIM / 128, T_TOK / 128, E_NUM), 256, 0, stream>>>(
        hidden, w2, counts, offsets, idx_list, wgt_list, out);
  }
}